// Round 2
// baseline (300.391 us; speedup 1.0000x reference)
//
#include <hip/hip_runtime.h>

// ---------------------------------------------------------------------------
// LIPAR attention, MI355X. B=4 N=4096 DIM=768 H=12 DH=64 S=16 M=256 C=48.
// Pipeline: rope table | x->bf16 | W->bf16^T | qkv GEMM (+rotary,+scale)
//           | KV transpose | chunked flash attention | output GEMM (+bias).
// ---------------------------------------------------------------------------

typedef float f32x4 __attribute__((ext_vector_type(4)));
typedef short bf16x8 __attribute__((ext_vector_type(8)));

#define DEV static __device__ __forceinline__

DEV short f2bf(float f) {  // RNE float->bf16 (bit pattern in short)
  unsigned u = __float_as_uint(f);
  return (short)((u + 0x7FFFu + ((u >> 16) & 1u)) >> 16);
}

DEV f32x4 fz4() { f32x4 z = {0.f, 0.f, 0.f, 0.f}; return z; }

DEV void gload16(const void* g, void* l) {
  // async global->LDS, 16B per lane; LDS dest = wave-uniform base + lane*16
  __builtin_amdgcn_global_load_lds((const __attribute__((address_space(1))) void*)g,
                                   (__attribute__((address_space(3))) void*)l, 16, 0, 0);
}

// ---------------- rope tables: cos/sin[pos][jm], pos<4096, jm<32 ------------
__global__ void __launch_bounds__(256) k_rope(float* __restrict__ cosT,
                                              float* __restrict__ sinT) {
  int idx = blockIdx.x * 256 + threadIdx.x;          // 131072 total
  int pos = idx >> 5, jm = idx & 31;
  float invf = exp2f(-(float)jm * (13.287712379549449f / 32.0f)); // 10000^(-jm/32)
  float th = (float)pos * invf;
  cosT[idx] = cosf(th);
  sinT[idx] = sinf(th);
}

// ---------------- x (fp32) -> xb (bf16) ------------------------------------
__global__ void __launch_bounds__(256) k_cvtx(const float* __restrict__ x,
                                              short* __restrict__ xb) {
  int i = (blockIdx.x * 256 + threadIdx.x) * 8;
  float4 a = *(const float4*)(x + i);
  float4 b = *(const float4*)(x + i + 4);
  bf16x8 v;
  v[0] = f2bf(a.x); v[1] = f2bf(a.y); v[2] = f2bf(a.z); v[3] = f2bf(a.w);
  v[4] = f2bf(b.x); v[5] = f2bf(b.y); v[6] = f2bf(b.z); v[7] = f2bf(b.w);
  *(bf16x8*)(xb + i) = v;
}

// -------- W (768x768 fp32) -> Wt[j][k] = bf16(W[k][j]) (two dest bufs) -----
__global__ void __launch_bounds__(256) k_transw(const float* __restrict__ Wq,
                                                const float* __restrict__ Wkv,
                                                const float* __restrict__ Wo,
                                                const float* __restrict__ Wo0,
                                                short* __restrict__ WtQKV,
                                                short* __restrict__ WtO) {
  __shared__ float t[64][65];
  int z = blockIdx.z;
  const float* src = (z == 0) ? Wq : (z == 1) ? Wkv : (z == 2) ? Wo : Wo0;
  short* dst = (z < 2) ? (WtQKV + (size_t)z * (768 * 768))
                       : (WtO + (size_t)(z - 2) * (768 * 768));
  int k0 = blockIdx.x * 64, j0 = blockIdx.y * 64;
  int tc = threadIdx.x & 63, tr = threadIdx.x >> 6;
#pragma unroll
  for (int i = 0; i < 16; i++) {
    int r = i * 4 + tr;
    t[tc][r] = src[(size_t)(k0 + r) * 768 + j0 + tc];   // coalesced read
  }
  __syncthreads();
#pragma unroll
  for (int i = 0; i < 16; i++) {
    int r = i * 4 + tr;
    dst[(size_t)(j0 + r) * 768 + k0 + tc] = f2bf(t[r][tc]); // coalesced write
  }
}

// ---------------- QKV GEMM 128x128 tile + fused rotary/scale ---------------
// cb 0..5 -> Q (heads 2cb+wc), cb 6..11 -> KV. Output layout [c][pos][64] bf16.
__global__ void __launch_bounds__(256, 2) k_gemm_qkv(
    const short* __restrict__ xb, const short* __restrict__ Wt,
    const float* __restrict__ cosT, const float* __restrict__ sinT,
    short* __restrict__ Qb, short* __restrict__ KVb) {
  __shared__ short Al[128 * 32];
  __shared__ short Bl[128 * 32];
  int r0 = blockIdx.x * 128;
  int cb = blockIdx.y;
  bool isQ = cb < 6;
  int cbl = isQ ? cb : cb - 6;
  const short* W = Wt + (isQ ? (size_t)0 : (size_t)(768 * 768));
  int j0 = cbl * 128;
  int tid = threadIdx.x, lane = tid & 63, wid = tid >> 6;
  int wr = wid >> 1, wc = wid & 1;
  int l15 = lane & 15, lg = lane >> 4;

  f32x4 acc[4][4];
#pragma unroll
  for (int i = 0; i < 4; i++)
#pragma unroll
    for (int j = 0; j < 4; j++) acc[i][j] = fz4();

  for (int kt = 0; kt < 24; kt++) {
    int k0 = kt * 32;
#pragma unroll
    for (int i = 0; i < 2; i++) {
      int g = i * 256 + tid;
      int row = g >> 2, oct = g & 3;
      gload16(xb + (size_t)(r0 + row) * 768 + k0 + oct * 8, &Al[(i * 256 + wid * 64) * 8]);
      gload16(W + (size_t)(j0 + row) * 768 + k0 + oct * 8, &Bl[(i * 256 + wid * 64) * 8]);
    }
    __syncthreads();
    bf16x8 af[4], bfr[4];
#pragma unroll
    for (int mr = 0; mr < 4; mr++)
      af[mr] = *(const bf16x8*)&Al[(wr * 64 + mr * 16 + l15) * 32 + lg * 8];
#pragma unroll
    for (int nc = 0; nc < 4; nc++)
      bfr[nc] = *(const bf16x8*)&Bl[(wc * 64 + nc * 16 + l15) * 32 + lg * 8];
#pragma unroll
    for (int mr = 0; mr < 4; mr++)
#pragma unroll
      for (int nc = 0; nc < 4; nc++)
        acc[mr][nc] = __builtin_amdgcn_mfma_f32_16x16x32_bf16(af[mr], bfr[nc], acc[mr][nc], 0, 0, 0);
    __syncthreads();
  }

  // epilogue: rotary (cols j and j^32 are acc[nc], acc[nc^2] in same lane)
  int h = 2 * cbl + wc;
  short* Ob = isQ ? Qb : KVb;
  float scl = isQ ? 0.125f : 1.0f;  // DH^-0.5
#pragma unroll
  for (int mr = 0; mr < 4; mr++) {
#pragma unroll
    for (int rg = 0; rg < 4; rg++) {
      int r = r0 + wr * 64 + mr * 16 + lg * 4 + rg;
      int b = r >> 12, pos = r & 4095;
      const float* cT = cosT + pos * 32;
      const float* sT = sinT + pos * 32;
      float c0 = cT[l15], s0 = sT[l15];
      float c1 = cT[16 + l15], s1 = sT[16 + l15];
      float v0 = acc[mr][0][rg], v1 = acc[mr][1][rg];
      float v2 = acc[mr][2][rg], v3 = acc[mr][3][rg];
      size_t base = ((size_t)((b * 12 + h) * 4096 + pos)) * 64 + l15;
      Ob[base]      = f2bf((v0 * c0 - v2 * s0) * scl);  // j<32: x*cos - x[j+32]*sin
      Ob[base + 16] = f2bf((v1 * c1 - v3 * s1) * scl);
      Ob[base + 32] = f2bf((v2 * c0 + v0 * s0) * scl);  // j>=32: x*cos + x[j-32]*sin
      Ob[base + 48] = f2bf((v3 * c1 + v1 * s1) * scl);
    }
  }
}

// ---------------- KV transpose: KVt[c][d][pos] = KVb[c][pos][d] ------------
__global__ void __launch_bounds__(256) k_transkv(const short* __restrict__ KVb,
                                                 short* __restrict__ KVt) {
  __shared__ short T[64][72];
  int c = blockIdx.x;
  int pt = blockIdx.y;           // 64-pos tile
  int t = threadIdx.x;
  int ch = t & 7, rr = t >> 3;   // chunk-of-8, row (0..31)
#pragma unroll
  for (int i = 0; i < 2; i++) {
    int p = rr + i * 32;
    bf16x8 v = *(const bf16x8*)&KVb[((size_t)c * 4096 + pt * 64 + p) * 64 + ch * 8];
    *(bf16x8*)&T[p][ch * 8] = v;
  }
  __syncthreads();
#pragma unroll
  for (int i = 0; i < 2; i++) {
    int d = rr + i * 32;
    bf16x8 v;
#pragma unroll
    for (int j = 0; j < 8; j++) v[j] = T[ch * 8 + j][d];
    *(bf16x8*)&KVt[((size_t)c * 64 + d) * 4096 + pt * 64 + ch * 8] = v;
  }
}

// ---------------- chunked flash attention ----------------------------------
// WG: (c, segment s, 64-query block); 4 waves x 16 queries. Keys processed in
// 128-key chunks with online softmax; scores live in 32 VGPRs. K frags from
// KVb (row-major), V^T frags from KVt (transposed), both via L2/L3. Only LDS:
// per-wave 16x32 P bounce tile (no block barriers at all).
template <int L>
__global__ void __launch_bounds__(256, 4) k_attn(const short* __restrict__ Qb,
                                                 const short* __restrict__ KVb,
                                                 const short* __restrict__ KVt,
                                                 short* __restrict__ AO) {
  constexpr int NC = L / 128;
  __shared__ short Pl[4][16 * 40]; // per-wave P bounce tile 16x32, stride 40
  int c = blockIdx.x;
  int s = (L == 256) ? 0 : (int)blockIdx.y + 1;
  int qb = blockIdx.z;
  int tid = threadIdx.x, lane = tid & 63, wid = tid >> 6;
  int l15 = lane & 15, lg = lane >> 4;
  const short* KVc = KVb + (size_t)c * 4096 * 64;
  const short* KVtc = KVt + (size_t)c * 64 * 4096;
  int Kbase = (L == 256) ? 0 : (s - 1) * 256;

  int q0 = s * 256 + qb * 64 + wid * 16;
  const short* Qr = Qb + ((size_t)c * 4096 + q0 + l15) * 64 + lg * 8;
  bf16x8 qf0 = *(const bf16x8*)Qr;
  bf16x8 qf1 = *(const bf16x8*)(Qr + 32);

  float m[4] = {-1e30f, -1e30f, -1e30f, -1e30f};
  float l[4] = {0.f, 0.f, 0.f, 0.f};
  f32x4 oacc[4] = {fz4(), fz4(), fz4(), fz4()};
  short* P = Pl[wid];

  for (int ch = 0; ch < NC; ch++) {
    int k0 = Kbase + ch * 128;
    // ---- QK^T for 8 key tiles (scores: row m=lg*4+reg -> query, col l15 -> key)
    f32x4 sc[8];
#pragma unroll
    for (int kt = 0; kt < 8; kt++) {
      const short* Kp = KVc + (size_t)(k0 + kt * 16 + l15) * 64 + lg * 8;
      bf16x8 kf0 = *(const bf16x8*)Kp;
      bf16x8 kf1 = *(const bf16x8*)(Kp + 32);
      f32x4 z = fz4();
      z = __builtin_amdgcn_mfma_f32_16x16x32_bf16(qf0, kf0, z, 0, 0, 0);
      z = __builtin_amdgcn_mfma_f32_16x16x32_bf16(qf1, kf1, z, 0, 0, 0);
      sc[kt] = z;
    }
    // ---- online softmax over this chunk (keys = cols across 16-lane groups)
    float cm[4];
#pragma unroll
    for (int r = 0; r < 4; r++) cm[r] = sc[0][r];
#pragma unroll
    for (int kt = 1; kt < 8; kt++)
#pragma unroll
      for (int r = 0; r < 4; r++) cm[r] = fmaxf(cm[r], sc[kt][r]);
#pragma unroll
    for (int r = 0; r < 4; r++)
#pragma unroll
      for (int off = 8; off > 0; off >>= 1)
        cm[r] = fmaxf(cm[r], __shfl_xor(cm[r], off, 64));
    float f[4];
#pragma unroll
    for (int r = 0; r < 4; r++) {
      float mn = fmaxf(m[r], cm[r]);
      f[r] = __expf(m[r] - mn);
      m[r] = mn;
    }
    float ss[4] = {0.f, 0.f, 0.f, 0.f};
#pragma unroll
    for (int kt = 0; kt < 8; kt++)
#pragma unroll
      for (int r = 0; r < 4; r++) {
        float e = __expf(sc[kt][r] - m[r]);
        sc[kt][r] = e;
        ss[r] += e;
      }
#pragma unroll
    for (int r = 0; r < 4; r++)
#pragma unroll
      for (int off = 8; off > 0; off >>= 1) ss[r] += __shfl_xor(ss[r], off, 64);
#pragma unroll
    for (int r = 0; r < 4; r++) l[r] = l[r] * f[r] + ss[r];
#pragma unroll
    for (int vt = 0; vt < 4; vt++)
#pragma unroll
      for (int r = 0; r < 4; r++) oacc[vt][r] *= f[r];
    // ---- PV per 32-key group: P bounce (per-wave LDS), V^T direct from KVt
#pragma unroll
    for (int u = 0; u < 4; u++) {
#pragma unroll
      for (int t2 = 0; t2 < 2; t2++)
#pragma unroll
        for (int rg = 0; rg < 4; rg++)
          P[(lg * 4 + rg) * 40 + t2 * 16 + l15] = f2bf(sc[2 * u + t2][rg]);
      bf16x8 pf = *(const bf16x8*)&P[l15 * 40 + lg * 8];
#pragma unroll
      for (int vt = 0; vt < 4; vt++) {
        bf16x8 vf = *(const bf16x8*)&KVtc[(size_t)(vt * 16 + l15) * 4096 + k0 + u * 32 + lg * 8];
        oacc[vt] = __builtin_amdgcn_mfma_f32_16x16x32_bf16(pf, vf, oacc[vt], 0, 0, 0);
      }
    }
  }

  int bq = c / 12, hh = c % 12;
  float rinv[4];
#pragma unroll
  for (int r = 0; r < 4; r++) rinv[r] = 1.0f / l[r];
#pragma unroll
  for (int vt = 0; vt < 4; vt++)
#pragma unroll
    for (int r = 0; r < 4; r++) {
      int mrow = lg * 4 + r;
      size_t row = (size_t)bq * 4096 + q0 + mrow;
      AO[row * 768 + hh * 64 + vt * 16 + l15] = f2bf(oacc[vt][r] * rinv[r]);
    }
}

// ---------------- output GEMM (+bias), W selected per token range ----------
__global__ void __launch_bounds__(256, 2) k_gemm_out(
    const short* __restrict__ AO, const short* __restrict__ Wt,
    const float* __restrict__ bo, const float* __restrict__ bo0,
    float* __restrict__ out) {
  __shared__ short Al[128 * 32];
  __shared__ short Bl[128 * 32];
  int r0 = blockIdx.x * 128;
  int j0 = blockIdx.y * 128;
  bool o0sel = (r0 & 4095) < 256;  // first 256 tokens of each batch -> Wo0/bo0
  const short* W = Wt + (o0sel ? (size_t)1 : (size_t)0) * (768 * 768);
  const float* bias = o0sel ? bo0 : bo;
  int tid = threadIdx.x, lane = tid & 63, wid = tid >> 6;
  int wr = wid >> 1, wc = wid & 1;
  int l15 = lane & 15, lg = lane >> 4;

  f32x4 acc[4][4];
#pragma unroll
  for (int i = 0; i < 4; i++)
#pragma unroll
    for (int j = 0; j < 4; j++) acc[i][j] = fz4();

  for (int kt = 0; kt < 24; kt++) {
    int k0 = kt * 32;
#pragma unroll
    for (int i = 0; i < 2; i++) {
      int g = i * 256 + tid;
      int row = g >> 2, oct = g & 3;
      gload16(AO + (size_t)(r0 + row) * 768 + k0 + oct * 8, &Al[(i * 256 + wid * 64) * 8]);
      gload16(W + (size_t)(j0 + row) * 768 + k0 + oct * 8, &Bl[(i * 256 + wid * 64) * 8]);
    }
    __syncthreads();
    bf16x8 af[4], bfr[4];
#pragma unroll
    for (int mr = 0; mr < 4; mr++)
      af[mr] = *(const bf16x8*)&Al[(wr * 64 + mr * 16 + l15) * 32 + lg * 8];
#pragma unroll
    for (int nc = 0; nc < 4; nc++)
      bfr[nc] = *(const bf16x8*)&Bl[(wc * 64 + nc * 16 + l15) * 32 + lg * 8];
#pragma unroll
    for (int mr = 0; mr < 4; mr++)
#pragma unroll
      for (int nc = 0; nc < 4; nc++)
        acc[mr][nc] = __builtin_amdgcn_mfma_f32_16x16x32_bf16(af[mr], bfr[nc], acc[mr][nc], 0, 0, 0);
    __syncthreads();
  }

  float bs[4];
#pragma unroll
  for (int nc = 0; nc < 4; nc++) bs[nc] = bias[j0 + wc * 64 + nc * 16 + l15];
#pragma unroll
  for (int mr = 0; mr < 4; mr++)
#pragma unroll
    for (int rg = 0; rg < 4; rg++) {
      size_t r = (size_t)r0 + wr * 64 + mr * 16 + lg * 4 + rg;
      float* op = out + r * 768 + j0 + wc * 64 + l15;
      op[0]  = acc[mr][0][rg] + bs[0];
      op[16] = acc[mr][1][rg] + bs[1];
      op[32] = acc[mr][2][rg] + bs[2];
      op[48] = acc[mr][3][rg] + bs[3];
    }
}

// ---------------------------------------------------------------------------
extern "C" void kernel_launch(void* const* d_in, const int* in_sizes, int n_in,
                              void* d_out, int out_size, void* d_ws, size_t ws_size,
                              hipStream_t stream) {
  (void)in_sizes; (void)n_in; (void)out_size; (void)ws_size;
  const float* x   = (const float*)d_in[0];
  const float* Wq  = (const float*)d_in[1];
  const float* Wkv = (const float*)d_in[2];
  const float* Wo  = (const float*)d_in[3];
  const float* bo  = (const float*)d_in[4];
  const float* Wo0 = (const float*)d_in[5];
  const float* bo0 = (const float*)d_in[6];
  float* out = (float*)d_out;

  char* ws = (char*)d_ws;
  // workspace layout (bytes), total 103,022,592 (~98.3 MiB):
  //   xb/AO 0..25165824 | Qb ..50331648 | KVb ..75497472 | KVt ..100663296
  //   (WtQKV + cos/sin live INSIDE the KVt region — dead before k_transkv)
  //   WtO 100663296..103022592
  short* xb    = (short*)(ws + 0);
  short* AO    = xb;  // alias: xb dead after qkv GEMM
  short* Qb    = (short*)(ws + 25165824);
  short* KVb   = (short*)(ws + 50331648);
  short* KVt   = (short*)(ws + 75497472);
  short* WtQKV = (short*)(ws + 75497472);            // alias into KVt region
  float* cosT  = (float*)(ws + 77856768);            // alias into KVt region
  float* sinT  = (float*)(ws + 78381056);            // alias into KVt region
  short* WtO   = (short*)(ws + 100663296);

  k_rope<<<512, 256, 0, stream>>>(cosT, sinT);
  k_cvtx<<<6144, 256, 0, stream>>>(x, xb);
  k_transw<<<dim3(12, 12, 4), 256, 0, stream>>>(Wq, Wkv, Wo, Wo0, WtQKV, WtO);
  k_gemm_qkv<<<dim3(128, 12), 256, 0, stream>>>(xb, WtQKV, cosT, sinT, Qb, KVb);
  k_transkv<<<dim3(48, 64), 256, 0, stream>>>(KVb, KVt);
  k_attn<256><<<dim3(48, 1, 4), 256, 0, stream>>>(Qb, KVb, KVt, AO);
  k_attn<512><<<dim3(48, 15, 4), 256, 0, stream>>>(Qb, KVb, KVt, AO);
  k_gemm_out<<<dim3(128, 6), 256, 0, stream>>>(AO, WtO, bo, bo0, out);
}

// Round 3
// 200.280 us; speedup vs baseline: 1.4999x; 1.4999x over previous
//
#include <hip/hip_runtime.h>

// ---------------------------------------------------------------------------
// LIPAR attention, MI355X. B=4 N=4096 DIM=768 H=12 DH=64 S=16 M=256 C=48.
// Pipeline: rope table | x->bf16 | W->bf16^T | qkv GEMM (+rotary,+scale)
//           | KV transpose (key-interleaved) | LDS-staged flash attention
//           | output GEMM (+bias).
// ---------------------------------------------------------------------------

typedef float f32x4 __attribute__((ext_vector_type(4)));
typedef short bf16x8 __attribute__((ext_vector_type(8)));

#define DEV static __device__ __forceinline__

DEV short f2bf(float f) {  // RNE float->bf16 (bit pattern in short)
  unsigned u = __float_as_uint(f);
  return (short)((u + 0x7FFFu + ((u >> 16) & 1u)) >> 16);
}

DEV f32x4 fz4() { f32x4 z = {0.f, 0.f, 0.f, 0.f}; return z; }

DEV void gload16(const void* g, void* l) {
  // async global->LDS, 16B per lane; LDS dest = wave-uniform base + lane*16
  __builtin_amdgcn_global_load_lds((const __attribute__((address_space(1))) void*)g,
                                   (__attribute__((address_space(3))) void*)l, 16, 0, 0);
}

// ---------------- rope tables: cos/sin[pos][jm], pos<4096, jm<32 ------------
__global__ void __launch_bounds__(256) k_rope(float* __restrict__ cosT,
                                              float* __restrict__ sinT) {
  int idx = blockIdx.x * 256 + threadIdx.x;          // 131072 total
  int pos = idx >> 5, jm = idx & 31;
  float invf = exp2f(-(float)jm * (13.287712379549449f / 32.0f)); // 10000^(-jm/32)
  float th = (float)pos * invf;
  cosT[idx] = cosf(th);
  sinT[idx] = sinf(th);
}

// ---------------- x (fp32) -> xb (bf16) ------------------------------------
__global__ void __launch_bounds__(256) k_cvtx(const float* __restrict__ x,
                                              short* __restrict__ xb) {
  int i = (blockIdx.x * 256 + threadIdx.x) * 8;
  float4 a = *(const float4*)(x + i);
  float4 b = *(const float4*)(x + i + 4);
  bf16x8 v;
  v[0] = f2bf(a.x); v[1] = f2bf(a.y); v[2] = f2bf(a.z); v[3] = f2bf(a.w);
  v[4] = f2bf(b.x); v[5] = f2bf(b.y); v[6] = f2bf(b.z); v[7] = f2bf(b.w);
  *(bf16x8*)(xb + i) = v;
}

// -------- W (768x768 fp32) -> Wt[j][k] = bf16(W[k][j]) (two dest bufs) -----
__global__ void __launch_bounds__(256) k_transw(const float* __restrict__ Wq,
                                                const float* __restrict__ Wkv,
                                                const float* __restrict__ Wo,
                                                const float* __restrict__ Wo0,
                                                short* __restrict__ WtQKV,
                                                short* __restrict__ WtO) {
  __shared__ float t[64][65];
  int z = blockIdx.z;
  const float* src = (z == 0) ? Wq : (z == 1) ? Wkv : (z == 2) ? Wo : Wo0;
  short* dst = (z < 2) ? (WtQKV + (size_t)z * (768 * 768))
                       : (WtO + (size_t)(z - 2) * (768 * 768));
  int k0 = blockIdx.x * 64, j0 = blockIdx.y * 64;
  int tc = threadIdx.x & 63, tr = threadIdx.x >> 6;
#pragma unroll
  for (int i = 0; i < 16; i++) {
    int r = i * 4 + tr;
    t[tc][r] = src[(size_t)(k0 + r) * 768 + j0 + tc];   // coalesced read
  }
  __syncthreads();
#pragma unroll
  for (int i = 0; i < 16; i++) {
    int r = i * 4 + tr;
    dst[(size_t)(j0 + r) * 768 + k0 + tc] = f2bf(t[r][tc]); // coalesced write
  }
}

// ---------------- QKV GEMM 128x128 tile + fused rotary/scale ---------------
// cb 0..5 -> Q (heads 2cb+wc), cb 6..11 -> KV. Output layout [c][pos][64] bf16.
__global__ void __launch_bounds__(256, 2) k_gemm_qkv(
    const short* __restrict__ xb, const short* __restrict__ Wt,
    const float* __restrict__ cosT, const float* __restrict__ sinT,
    short* __restrict__ Qb, short* __restrict__ KVb) {
  __shared__ short Al[128 * 32];
  __shared__ short Bl[128 * 32];
  int r0 = blockIdx.x * 128;
  int cb = blockIdx.y;
  bool isQ = cb < 6;
  int cbl = isQ ? cb : cb - 6;
  const short* W = Wt + (isQ ? (size_t)0 : (size_t)(768 * 768));
  int j0 = cbl * 128;
  int tid = threadIdx.x, lane = tid & 63, wid = tid >> 6;
  int wr = wid >> 1, wc = wid & 1;
  int l15 = lane & 15, lg = lane >> 4;

  f32x4 acc[4][4];
#pragma unroll
  for (int i = 0; i < 4; i++)
#pragma unroll
    for (int j = 0; j < 4; j++) acc[i][j] = fz4();

  for (int kt = 0; kt < 24; kt++) {
    int k0 = kt * 32;
#pragma unroll
    for (int i = 0; i < 2; i++) {
      int g = i * 256 + tid;
      int row = g >> 2, oct = g & 3;
      gload16(xb + (size_t)(r0 + row) * 768 + k0 + oct * 8, &Al[(i * 256 + wid * 64) * 8]);
      gload16(W + (size_t)(j0 + row) * 768 + k0 + oct * 8, &Bl[(i * 256 + wid * 64) * 8]);
    }
    __syncthreads();
    bf16x8 af[4], bfr[4];
#pragma unroll
    for (int mr = 0; mr < 4; mr++)
      af[mr] = *(const bf16x8*)&Al[(wr * 64 + mr * 16 + l15) * 32 + lg * 8];
#pragma unroll
    for (int nc = 0; nc < 4; nc++)
      bfr[nc] = *(const bf16x8*)&Bl[(wc * 64 + nc * 16 + l15) * 32 + lg * 8];
#pragma unroll
    for (int mr = 0; mr < 4; mr++)
#pragma unroll
      for (int nc = 0; nc < 4; nc++)
        acc[mr][nc] = __builtin_amdgcn_mfma_f32_16x16x32_bf16(af[mr], bfr[nc], acc[mr][nc], 0, 0, 0);
    __syncthreads();
  }

  // epilogue: rotary (cols j and j^32 are acc[nc], acc[nc^2] in same lane)
  int h = 2 * cbl + wc;
  short* Ob = isQ ? Qb : KVb;
  float scl = isQ ? 0.125f : 1.0f;  // DH^-0.5
#pragma unroll
  for (int mr = 0; mr < 4; mr++) {
#pragma unroll
    for (int rg = 0; rg < 4; rg++) {
      int r = r0 + wr * 64 + mr * 16 + lg * 4 + rg;
      int b = r >> 12, pos = r & 4095;
      const float* cT = cosT + pos * 32;
      const float* sT = sinT + pos * 32;
      float c0 = cT[l15], s0 = sT[l15];
      float c1 = cT[16 + l15], s1 = sT[16 + l15];
      float v0 = acc[mr][0][rg], v1 = acc[mr][1][rg];
      float v2 = acc[mr][2][rg], v3 = acc[mr][3][rg];
      size_t base = ((size_t)((b * 12 + h) * 4096 + pos)) * 64 + l15;
      Ob[base]      = f2bf((v0 * c0 - v2 * s0) * scl);  // j<32: x*cos - x[j+32]*sin
      Ob[base + 16] = f2bf((v1 * c1 - v3 * s1) * scl);
      Ob[base + 32] = f2bf((v2 * c0 + v0 * s0) * scl);  // j>=32: x*cos + x[j-32]*sin
      Ob[base + 48] = f2bf((v3 * c1 + v1 * s1) * scl);
    }
  }
}

// ------ KV transpose, key-interleaved: KVt[c][d][g*32+cc] = KV[c][p][d] ----
// with p = g*32 + (cc&1)*16 + (cc>>1)  (so packed bf16 pairs (2*l15,2*l15+1)
// in the attention P tile line up with tiles kt=2u,2u+1 key order).
__global__ void __launch_bounds__(256) k_transkv(const short* __restrict__ KVb,
                                                 short* __restrict__ KVt) {
  __shared__ short T[64][72];
  int c = blockIdx.x;
  int pt = blockIdx.y;           // 64-pos tile
  int t = threadIdx.x;
  int ch = t & 7, rr = t >> 3;   // chunk-of-8, row (0..31)
#pragma unroll
  for (int i = 0; i < 2; i++) {
    int p = rr + i * 32;
    bf16x8 v = *(const bf16x8*)&KVb[((size_t)c * 4096 + pt * 64 + p) * 64 + ch * 8];
    *(bf16x8*)&T[p][ch * 8] = v;
  }
  __syncthreads();
#pragma unroll
  for (int i = 0; i < 2; i++) {
    int d = rr + i * 32;
    bf16x8 v;
#pragma unroll
    for (int j = 0; j < 8; j++) {
      int cc = ch * 8 + j;
      int g = cc >> 5, w = cc & 31;
      int p = g * 32 + ((w & 1) << 4) + (w >> 1);
      v[j] = T[p][d];
    }
    *(bf16x8*)&KVt[((size_t)c * 64 + d) * 4096 + pt * 64 + ch * 8] = v;
  }
}

// ---------------- LDS-staged chunked flash attention -----------------------
// WG: (c, seg s, 64-query block); 4 waves x 16 q. 64-key chunks, K+V staged in
// LDS via global_load_lds (double-buffered, XOR-swizzled via pre-swizzled
// global source), online softmax, P bounced per-wave as packed b32.
#define STAGE(buf, kk0)                                                        \
  {                                                                            \
    _Pragma("unroll") for (int i = 0; i < 2; i++) {                            \
      gload16(KVc + (size_t)((kk0) + i * 32 + krow) * 128 + ksrccol,           \
              (char*)Kl[buf] + i * 4096 + wid * 1024);                         \
      gload16(KVtc + ((size_t)(i * 32 + krow) * 4096 + (kk0)) * 2 + ksrccol,   \
              (char*)Vl[buf] + i * 4096 + wid * 1024);                         \
    }                                                                          \
  }

template <int L>
__global__ void __launch_bounds__(256, 4) k_attn(const short* __restrict__ Qb,
                                                 const short* __restrict__ KVbp,
                                                 const short* __restrict__ KVtp,
                                                 short* __restrict__ AO) {
  constexpr int NC = L / 64;
  __shared__ short Kl[2][4096];    // [64 key][64 d] rows 128B, XOR-swizzled
  __shared__ short Vl[2][4096];    // [64 d][64 pos(interleaved)] 128B rows
  __shared__ short Pl[4][16 * 40]; // per-wave P tile 16x32(interleaved), pad 40
  int c = blockIdx.x;
  int s = (L == 256) ? 0 : (int)blockIdx.y + 1;
  int qb = blockIdx.z;
  int tid = threadIdx.x, lane = tid & 63, wid = tid >> 6;
  int l15 = lane & 15, lg = lane >> 4;
  const char* KVc = (const char*)(KVbp + (size_t)c * 4096 * 64);
  const char* KVtc = (const char*)(KVtp + (size_t)c * 64 * 4096);
  int Kbase = (L == 256) ? 0 : (s - 1) * 256;

  // staging constants: row within 32-row issue, 16B chunk, swizzled src col
  int krow = tid >> 3;                 // 0..31
  int ksrccol = ((tid & 7) * 16) ^ ((krow & 7) << 4);
  int swz = (l15 & 7) << 4;            // read-side XOR

  int q0 = s * 256 + qb * 64 + wid * 16;
  const short* Qr = Qb + ((size_t)c * 4096 + q0 + l15) * 64 + lg * 8;
  bf16x8 qf0 = *(const bf16x8*)Qr;
  bf16x8 qf1 = *(const bf16x8*)(Qr + 32);

  float m[4] = {-1e30f, -1e30f, -1e30f, -1e30f};
  float l[4] = {0.f, 0.f, 0.f, 0.f};
  f32x4 oacc[4] = {fz4(), fz4(), fz4(), fz4()};
  char* P = (char*)Pl[wid];

  STAGE(0, Kbase)
  for (int ch = 0; ch < NC; ch++) {
    int cb = ch & 1;
    __syncthreads();                       // drains vmcnt(0): buf[cb] ready
    if (ch + 1 < NC) STAGE(cb ^ 1, Kbase + (ch + 1) * 64)
    const char* Kb_ = (const char*)Kl[cb];
    const char* Vb_ = (const char*)Vl[cb];
    // ---- QK^T: rows m=lg*4+reg -> query, col l15 -> key (tile kt)
    f32x4 sc[4];
#pragma unroll
    for (int kt = 0; kt < 4; kt++) {
      const char* Kp = Kb_ + (kt * 16 + l15) * 128;
      bf16x8 kf0 = *(const bf16x8*)(Kp + ((lg * 16) ^ swz));
      bf16x8 kf1 = *(const bf16x8*)(Kp + ((64 + lg * 16) ^ swz));
      f32x4 z = fz4();
      z = __builtin_amdgcn_mfma_f32_16x16x32_bf16(qf0, kf0, z, 0, 0, 0);
      z = __builtin_amdgcn_mfma_f32_16x16x32_bf16(qf1, kf1, z, 0, 0, 0);
      sc[kt] = z;
    }
    // ---- online softmax over this chunk (keys = cols across 16-lane groups)
    float cm[4];
#pragma unroll
    for (int r = 0; r < 4; r++)
      cm[r] = fmaxf(fmaxf(sc[0][r], sc[1][r]), fmaxf(sc[2][r], sc[3][r]));
#pragma unroll
    for (int r = 0; r < 4; r++)
#pragma unroll
      for (int off = 8; off > 0; off >>= 1)
        cm[r] = fmaxf(cm[r], __shfl_xor(cm[r], off, 64));
    float f[4];
#pragma unroll
    for (int r = 0; r < 4; r++) {
      float mn = fmaxf(m[r], cm[r]);
      f[r] = __expf(m[r] - mn);
      m[r] = mn;
    }
    float ss[4] = {0.f, 0.f, 0.f, 0.f};
#pragma unroll
    for (int kt = 0; kt < 4; kt++)
#pragma unroll
      for (int r = 0; r < 4; r++) {
        float e = __expf(sc[kt][r] - m[r]);
        sc[kt][r] = e;
        ss[r] += e;
      }
#pragma unroll
    for (int r = 0; r < 4; r++)
#pragma unroll
      for (int off = 8; off > 0; off >>= 1) ss[r] += __shfl_xor(ss[r], off, 64);
#pragma unroll
    for (int r = 0; r < 4; r++) l[r] = l[r] * f[r] + ss[r];
#pragma unroll
    for (int vt = 0; vt < 4; vt++)
#pragma unroll
      for (int r = 0; r < 4; r++) oacc[vt][r] *= f[r];
    // ---- PV per 32-key group: packed-b32 P bounce + swizzled V from LDS
#pragma unroll
    for (int u = 0; u < 2; u++) {
#pragma unroll
      for (int rg = 0; rg < 4; rg++) {
        unsigned pk = (unsigned short)f2bf(sc[2 * u][rg]) |
                      ((unsigned)(unsigned short)f2bf(sc[2 * u + 1][rg]) << 16);
        *(unsigned*)(P + (lg * 4 + rg) * 80 + l15 * 4) = pk;
      }
      bf16x8 pf = *(const bf16x8*)(P + l15 * 80 + lg * 16);
#pragma unroll
      for (int vt = 0; vt < 4; vt++) {
        bf16x8 vf = *(const bf16x8*)(Vb_ + (vt * 16 + l15) * 128 +
                                     ((u * 64 + lg * 16) ^ swz));
        oacc[vt] = __builtin_amdgcn_mfma_f32_16x16x32_bf16(pf, vf, oacc[vt], 0, 0, 0);
      }
    }
  }

  int bq = c / 12, hh = c % 12;
  float rinv[4];
#pragma unroll
  for (int r = 0; r < 4; r++) rinv[r] = 1.0f / l[r];
#pragma unroll
  for (int vt = 0; vt < 4; vt++)
#pragma unroll
    for (int r = 0; r < 4; r++) {
      int mrow = lg * 4 + r;
      size_t row = (size_t)bq * 4096 + q0 + mrow;
      AO[row * 768 + hh * 64 + vt * 16 + l15] = f2bf(oacc[vt][r] * rinv[r]);
    }
}

// ---------------- output GEMM (+bias), W selected per token range ----------
__global__ void __launch_bounds__(256, 2) k_gemm_out(
    const short* __restrict__ AO, const short* __restrict__ Wt,
    const float* __restrict__ bo, const float* __restrict__ bo0,
    float* __restrict__ out) {
  __shared__ short Al[128 * 32];
  __shared__ short Bl[128 * 32];
  int r0 = blockIdx.x * 128;
  int j0 = blockIdx.y * 128;
  bool o0sel = (r0 & 4095) < 256;  // first 256 tokens of each batch -> Wo0/bo0
  const short* W = Wt + (o0sel ? (size_t)1 : (size_t)0) * (768 * 768);
  const float* bias = o0sel ? bo0 : bo;
  int tid = threadIdx.x, lane = tid & 63, wid = tid >> 6;
  int wr = wid >> 1, wc = wid & 1;
  int l15 = lane & 15, lg = lane >> 4;

  f32x4 acc[4][4];
#pragma unroll
  for (int i = 0; i < 4; i++)
#pragma unroll
    for (int j = 0; j < 4; j++) acc[i][j] = fz4();

  for (int kt = 0; kt < 24; kt++) {
    int k0 = kt * 32;
#pragma unroll
    for (int i = 0; i < 2; i++) {
      int g = i * 256 + tid;
      int row = g >> 2, oct = g & 3;
      gload16(AO + (size_t)(r0 + row) * 768 + k0 + oct * 8, &Al[(i * 256 + wid * 64) * 8]);
      gload16(W + (size_t)(j0 + row) * 768 + k0 + oct * 8, &Bl[(i * 256 + wid * 64) * 8]);
    }
    __syncthreads();
    bf16x8 af[4], bfr[4];
#pragma unroll
    for (int mr = 0; mr < 4; mr++)
      af[mr] = *(const bf16x8*)&Al[(wr * 64 + mr * 16 + l15) * 32 + lg * 8];
#pragma unroll
    for (int nc = 0; nc < 4; nc++)
      bfr[nc] = *(const bf16x8*)&Bl[(wc * 64 + nc * 16 + l15) * 32 + lg * 8];
#pragma unroll
    for (int mr = 0; mr < 4; mr++)
#pragma unroll
      for (int nc = 0; nc < 4; nc++)
        acc[mr][nc] = __builtin_amdgcn_mfma_f32_16x16x32_bf16(af[mr], bfr[nc], acc[mr][nc], 0, 0, 0);
    __syncthreads();
  }

  float bs[4];
#pragma unroll
  for (int nc = 0; nc < 4; nc++) bs[nc] = bias[j0 + wc * 64 + nc * 16 + l15];
#pragma unroll
  for (int mr = 0; mr < 4; mr++)
#pragma unroll
    for (int rg = 0; rg < 4; rg++) {
      size_t r = (size_t)r0 + wr * 64 + mr * 16 + lg * 4 + rg;
      float* op = out + r * 768 + j0 + wc * 64 + l15;
      op[0]  = acc[mr][0][rg] + bs[0];
      op[16] = acc[mr][1][rg] + bs[1];
      op[32] = acc[mr][2][rg] + bs[2];
      op[48] = acc[mr][3][rg] + bs[3];
    }
}

// ---------------------------------------------------------------------------
extern "C" void kernel_launch(void* const* d_in, const int* in_sizes, int n_in,
                              void* d_out, int out_size, void* d_ws, size_t ws_size,
                              hipStream_t stream) {
  (void)in_sizes; (void)n_in; (void)out_size; (void)ws_size;
  const float* x   = (const float*)d_in[0];
  const float* Wq  = (const float*)d_in[1];
  const float* Wkv = (const float*)d_in[2];
  const float* Wo  = (const float*)d_in[3];
  const float* bo  = (const float*)d_in[4];
  const float* Wo0 = (const float*)d_in[5];
  const float* bo0 = (const float*)d_in[6];
  float* out = (float*)d_out;

  char* ws = (char*)d_ws;
  // workspace layout (bytes), total 103,022,592 (~98.3 MiB):
  //   xb/AO 0..25165824 | Qb ..50331648 | KVb ..75497472 | KVt ..100663296
  //   (WtQKV + cos/sin live INSIDE the KVt region — dead before k_transkv)
  //   WtO 100663296..103022592
  short* xb    = (short*)(ws + 0);
  short* AO    = xb;  // alias: xb dead after qkv GEMM
  short* Qb    = (short*)(ws + 25165824);
  short* KVb   = (short*)(ws + 50331648);
  short* KVt   = (short*)(ws + 75497472);
  short* WtQKV = (short*)(ws + 75497472);            // alias into KVt region
  float* cosT  = (float*)(ws + 77856768);            // alias into KVt region
  float* sinT  = (float*)(ws + 78381056);            // alias into KVt region
  short* WtO   = (short*)(ws + 100663296);

  k_rope<<<512, 256, 0, stream>>>(cosT, sinT);
  k_cvtx<<<6144, 256, 0, stream>>>(x, xb);
  k_transw<<<dim3(12, 12, 4), 256, 0, stream>>>(Wq, Wkv, Wo, Wo0, WtQKV, WtO);
  k_gemm_qkv<<<dim3(128, 12), 256, 0, stream>>>(xb, WtQKV, cosT, sinT, Qb, KVb);
  k_transkv<<<dim3(48, 64), 256, 0, stream>>>(KVb, KVt);
  k_attn<256><<<dim3(48, 1, 4), 256, 0, stream>>>(Qb, KVb, KVt, AO);
  k_attn<512><<<dim3(48, 15, 4), 256, 0, stream>>>(Qb, KVb, KVt, AO);
  k_gemm_out<<<dim3(128, 6), 256, 0, stream>>>(AO, WtO, bo, bo0, out);
}

// Round 4
// 189.556 us; speedup vs baseline: 1.5847x; 1.0566x over previous
//
#include <hip/hip_runtime.h>
#include <hip/hip_bf16.h>

// ---------------------------------------------------------------------------
// LIPAR attention, MI355X. B=4 N=4096 DIM=768 H=12 DH=64 S=16 M=256 C=48.
// Pipeline: rope table | x->bf16 | W->bf16^T | qkv GEMM (+rotary,+scale,
//           Q pre-scaled by log2e for exp2-domain softmax) | KV transpose
//           (key-interleaved) | merged LDS-staged flash attention (128q/block,
//           XCD-swizzled) | output GEMM (+bias).
// ---------------------------------------------------------------------------

typedef float f32x4 __attribute__((ext_vector_type(4)));
typedef short bf16x8 __attribute__((ext_vector_type(8)));

#define DEV static __device__ __forceinline__

DEV short f2bf(float f) {  // RNE float->bf16 via HW cvt
  union { __hip_bfloat16 h; unsigned short u; } cv;
  cv.h = __float2bfloat16(f);
  return (short)cv.u;
}

DEV f32x4 fz4() { f32x4 z = {0.f, 0.f, 0.f, 0.f}; return z; }

DEV void gload16(const void* g, void* l) {
  // async global->LDS, 16B per lane; LDS dest = wave-uniform base + lane*16
  __builtin_amdgcn_global_load_lds((const __attribute__((address_space(1))) void*)g,
                                   (__attribute__((address_space(3))) void*)l, 16, 0, 0);
}

// ---------------- rope tables: cos/sin[pos][jm], pos<4096, jm<32 ------------
__global__ void __launch_bounds__(256) k_rope(float* __restrict__ cosT,
                                              float* __restrict__ sinT) {
  int idx = blockIdx.x * 256 + threadIdx.x;          // 131072 total
  int pos = idx >> 5, jm = idx & 31;
  float invf = exp2f(-(float)jm * (13.287712379549449f / 32.0f)); // 10000^(-jm/32)
  float th = (float)pos * invf;
  cosT[idx] = cosf(th);
  sinT[idx] = sinf(th);
}

// ---------------- x (fp32) -> xb (bf16) ------------------------------------
__global__ void __launch_bounds__(256) k_cvtx(const float* __restrict__ x,
                                              short* __restrict__ xb) {
  int i = (blockIdx.x * 256 + threadIdx.x) * 8;
  float4 a = *(const float4*)(x + i);
  float4 b = *(const float4*)(x + i + 4);
  bf16x8 v;
  v[0] = f2bf(a.x); v[1] = f2bf(a.y); v[2] = f2bf(a.z); v[3] = f2bf(a.w);
  v[4] = f2bf(b.x); v[5] = f2bf(b.y); v[6] = f2bf(b.z); v[7] = f2bf(b.w);
  *(bf16x8*)(xb + i) = v;
}

// -------- W (768x768 fp32) -> Wt[j][k] = bf16(W[k][j]) (two dest bufs) -----
__global__ void __launch_bounds__(256) k_transw(const float* __restrict__ Wq,
                                                const float* __restrict__ Wkv,
                                                const float* __restrict__ Wo,
                                                const float* __restrict__ Wo0,
                                                short* __restrict__ WtQKV,
                                                short* __restrict__ WtO) {
  __shared__ float t[64][65];
  int z = blockIdx.z;
  const float* src = (z == 0) ? Wq : (z == 1) ? Wkv : (z == 2) ? Wo : Wo0;
  short* dst = (z < 2) ? (WtQKV + (size_t)z * (768 * 768))
                       : (WtO + (size_t)(z - 2) * (768 * 768));
  int k0 = blockIdx.x * 64, j0 = blockIdx.y * 64;
  int tc = threadIdx.x & 63, tr = threadIdx.x >> 6;
#pragma unroll
  for (int i = 0; i < 16; i++) {
    int r = i * 4 + tr;
    t[tc][r] = src[(size_t)(k0 + r) * 768 + j0 + tc];   // coalesced read
  }
  __syncthreads();
#pragma unroll
  for (int i = 0; i < 16; i++) {
    int r = i * 4 + tr;
    dst[(size_t)(j0 + r) * 768 + k0 + tc] = f2bf(t[r][tc]); // coalesced write
  }
}

// ---------------- QKV GEMM 128x128 tile + fused rotary/scale ---------------
// cb 0..5 -> Q (heads 2cb+wc), cb 6..11 -> KV. Output layout [c][pos][64] bf16.
// Q additionally scaled by log2e so attention softmax can use exp2.
__global__ void __launch_bounds__(256, 2) k_gemm_qkv(
    const short* __restrict__ xb, const short* __restrict__ Wt,
    const float* __restrict__ cosT, const float* __restrict__ sinT,
    short* __restrict__ Qb, short* __restrict__ KVb) {
  __shared__ short Al[128 * 32];
  __shared__ short Bl[128 * 32];
  int r0 = blockIdx.x * 128;
  int cb = blockIdx.y;
  bool isQ = cb < 6;
  int cbl = isQ ? cb : cb - 6;
  const short* W = Wt + (isQ ? (size_t)0 : (size_t)(768 * 768));
  int j0 = cbl * 128;
  int tid = threadIdx.x, lane = tid & 63, wid = tid >> 6;
  int wr = wid >> 1, wc = wid & 1;
  int l15 = lane & 15, lg = lane >> 4;

  f32x4 acc[4][4];
#pragma unroll
  for (int i = 0; i < 4; i++)
#pragma unroll
    for (int j = 0; j < 4; j++) acc[i][j] = fz4();

  for (int kt = 0; kt < 24; kt++) {
    int k0 = kt * 32;
#pragma unroll
    for (int i = 0; i < 2; i++) {
      int g = i * 256 + tid;
      int row = g >> 2, oct = g & 3;
      gload16(xb + (size_t)(r0 + row) * 768 + k0 + oct * 8, &Al[(i * 256 + wid * 64) * 8]);
      gload16(W + (size_t)(j0 + row) * 768 + k0 + oct * 8, &Bl[(i * 256 + wid * 64) * 8]);
    }
    __syncthreads();
    bf16x8 af[4], bfr[4];
#pragma unroll
    for (int mr = 0; mr < 4; mr++)
      af[mr] = *(const bf16x8*)&Al[(wr * 64 + mr * 16 + l15) * 32 + lg * 8];
#pragma unroll
    for (int nc = 0; nc < 4; nc++)
      bfr[nc] = *(const bf16x8*)&Bl[(wc * 64 + nc * 16 + l15) * 32 + lg * 8];
#pragma unroll
    for (int mr = 0; mr < 4; mr++)
#pragma unroll
      for (int nc = 0; nc < 4; nc++)
        acc[mr][nc] = __builtin_amdgcn_mfma_f32_16x16x32_bf16(af[mr], bfr[nc], acc[mr][nc], 0, 0, 0);
    __syncthreads();
  }

  // epilogue: rotary (cols j and j^32 are acc[nc], acc[nc^2] in same lane)
  int h = 2 * cbl + wc;
  short* Ob = isQ ? Qb : KVb;
  float scl = isQ ? 0.18033688011112042f : 1.0f;  // DH^-0.5 * log2(e)
#pragma unroll
  for (int mr = 0; mr < 4; mr++) {
#pragma unroll
    for (int rg = 0; rg < 4; rg++) {
      int r = r0 + wr * 64 + mr * 16 + lg * 4 + rg;
      int b = r >> 12, pos = r & 4095;
      const float* cT = cosT + pos * 32;
      const float* sT = sinT + pos * 32;
      float c0 = cT[l15], s0 = sT[l15];
      float c1 = cT[16 + l15], s1 = sT[16 + l15];
      float v0 = acc[mr][0][rg], v1 = acc[mr][1][rg];
      float v2 = acc[mr][2][rg], v3 = acc[mr][3][rg];
      size_t base = ((size_t)((b * 12 + h) * 4096 + pos)) * 64 + l15;
      Ob[base]      = f2bf((v0 * c0 - v2 * s0) * scl);  // j<32: x*cos - x[j+32]*sin
      Ob[base + 16] = f2bf((v1 * c1 - v3 * s1) * scl);
      Ob[base + 32] = f2bf((v2 * c0 + v0 * s0) * scl);  // j>=32: x*cos + x[j-32]*sin
      Ob[base + 48] = f2bf((v3 * c1 + v1 * s1) * scl);
    }
  }
}

// ------ KV transpose, key-interleaved: KVt[c][d][g*32+cc] = KV[c][p][d] ----
// with p = g*32 + (cc&1)*16 + (cc>>1)  (so packed bf16 pairs (2*l15,2*l15+1)
// in the attention P tile line up with tiles kt=2u,2u+1 key order).
__global__ void __launch_bounds__(256) k_transkv(const short* __restrict__ KVb,
                                                 short* __restrict__ KVt) {
  __shared__ short T[64][72];
  int c = blockIdx.x;
  int pt = blockIdx.y;           // 64-pos tile
  int t = threadIdx.x;
  int ch = t & 7, rr = t >> 3;   // chunk-of-8, row (0..31)
#pragma unroll
  for (int i = 0; i < 2; i++) {
    int p = rr + i * 32;
    bf16x8 v = *(const bf16x8*)&KVb[((size_t)c * 4096 + pt * 64 + p) * 64 + ch * 8];
    *(bf16x8*)&T[p][ch * 8] = v;
  }
  __syncthreads();
#pragma unroll
  for (int i = 0; i < 2; i++) {
    int d = rr + i * 32;
    bf16x8 v;
#pragma unroll
    for (int j = 0; j < 8; j++) {
      int cc = ch * 8 + j;
      int g = cc >> 5, w = cc & 31;
      int p = g * 32 + ((w & 1) << 4) + (w >> 1);
      v[j] = T[p][d];
    }
    *(bf16x8*)&KVt[((size_t)c * 64 + d) * 4096 + pt * 64 + ch * 8] = v;
  }
}

// ---------------- merged LDS-staged flash attention ------------------------
// One dispatch, 1536 blocks. Per c: 32 entries (2 for s=0, 30 for s=1..15).
// Block = 128 queries (4 waves x 32q, 2 q-tiles each). 64-key chunks staged
// (double-buffered global_load_lds, XOR-swizzled via pre-swizzled source).
// exp2-domain online softmax with defer-max (THR=8 log2-units).
#define STAGE(buf, kk0)                                                        \
  {                                                                            \
    _Pragma("unroll") for (int i = 0; i < 2; i++) {                            \
      gload16(KVc + (size_t)((kk0) + i * 32 + krow) * 128 + ksrccol,           \
              (char*)Kl[buf] + i * 4096 + wid * 1024);                         \
      gload16(KVtc + ((size_t)(i * 32 + krow) * 4096 + (kk0)) * 2 + ksrccol,   \
              (char*)Vl[buf] + i * 4096 + wid * 1024);                         \
    }                                                                          \
  }

__global__ void __launch_bounds__(256, 3) k_attn(const short* __restrict__ Qb,
                                                 const short* __restrict__ KVbp,
                                                 const short* __restrict__ KVtp,
                                                 short* __restrict__ AO) {
  __shared__ short Kl[2][4096];    // [64 key][64 d] rows 128B, XOR-swizzled
  __shared__ short Vl[2][4096];    // [64 d][64 pos(interleaved)] 128B rows
  __shared__ short Pl[4][16 * 40]; // per-wave P tile 16x32(interleaved), pad 40
  // XCD-bijective swizzle: 1536 blocks, 192/XCD, c-major so one c's KV stays
  // in one XCD's L2 (adjacent segments share half their keys).
  int bid = blockIdx.x;
  int orig = (bid & 7) * 192 + (bid >> 3);
  int c = orig >> 5;
  int e = orig & 31;               // 0,1 -> s=0 halves; 2..31 -> s=1..15 halves
  int s = (e < 2) ? 0 : ((e - 2) >> 1) + 1;
  int qh = (e < 2) ? e : (e - 2) & 1;
  int NC = (s == 0) ? 4 : 8;
  int Kbase = (s == 0) ? 0 : (s - 1) * 256;

  int tid = threadIdx.x, lane = tid & 63, wid = tid >> 6;
  int l15 = lane & 15, lg = lane >> 4;
  const char* KVc = (const char*)(KVbp + (size_t)c * 4096 * 64);
  const char* KVtc = (const char*)(KVtp + (size_t)c * 64 * 4096);

  // staging constants: row within 32-row issue, 16B chunk, swizzled src col
  int krow = tid >> 3;                 // 0..31
  int ksrccol = ((tid & 7) * 16) ^ ((krow & 7) << 4);
  int swz = (l15 & 7) << 4;            // read-side XOR

  int q0 = s * 256 + qh * 128 + wid * 32;
  bf16x8 qf[2][2];
#pragma unroll
  for (int qt = 0; qt < 2; qt++) {
    const short* Qr = Qb + ((size_t)c * 4096 + q0 + qt * 16 + l15) * 64 + lg * 8;
    qf[qt][0] = *(const bf16x8*)Qr;
    qf[qt][1] = *(const bf16x8*)(Qr + 32);
  }

  float m[2][4], l[2][4];
  f32x4 oacc[2][4];
#pragma unroll
  for (int qt = 0; qt < 2; qt++)
#pragma unroll
    for (int r = 0; r < 4; r++) { m[qt][r] = -1e30f; l[qt][r] = 0.f; }
#pragma unroll
  for (int qt = 0; qt < 2; qt++)
#pragma unroll
    for (int vt = 0; vt < 4; vt++) oacc[qt][vt] = fz4();
  char* P = (char*)Pl[wid];

  STAGE(0, Kbase)
  for (int ch = 0; ch < NC; ch++) {
    int cb = ch & 1;
    __syncthreads();                       // drains vmcnt(0): buf[cb] ready
    if (ch + 1 < NC) STAGE(cb ^ 1, Kbase + (ch + 1) * 64)
    const char* Kb_ = (const char*)Kl[cb];
    const char* Vb_ = (const char*)Vl[cb];
    // ---- QK^T: rows = query (lg*4+reg), col l15 = key (within tile kt)
    f32x4 sc[2][4];
#pragma unroll
    for (int kt = 0; kt < 4; kt++) {
      const char* Kp = Kb_ + (kt * 16 + l15) * 128;
      bf16x8 kf0 = *(const bf16x8*)(Kp + ((lg * 16) ^ swz));
      bf16x8 kf1 = *(const bf16x8*)(Kp + ((64 + lg * 16) ^ swz));
#pragma unroll
      for (int qt = 0; qt < 2; qt++) {
        f32x4 z = fz4();
        z = __builtin_amdgcn_mfma_f32_16x16x32_bf16(qf[qt][0], kf0, z, 0, 0, 0);
        z = __builtin_amdgcn_mfma_f32_16x16x32_bf16(qf[qt][1], kf1, z, 0, 0, 0);
        sc[qt][kt] = z;
      }
    }
    // ---- online softmax (exp2 domain; scores pre-scaled by log2e)
    float cm[2][4];
#pragma unroll
    for (int qt = 0; qt < 2; qt++)
#pragma unroll
      for (int r = 0; r < 4; r++)
        cm[qt][r] = fmaxf(fmaxf(sc[qt][0][r], sc[qt][1][r]),
                          fmaxf(sc[qt][2][r], sc[qt][3][r]));
#pragma unroll
    for (int qt = 0; qt < 2; qt++)
#pragma unroll
      for (int r = 0; r < 4; r++)
#pragma unroll
        for (int off = 8; off > 0; off >>= 1)
          cm[qt][r] = fmaxf(cm[qt][r], __shfl_xor(cm[qt][r], off, 64));
    float dm = -1e30f;
#pragma unroll
    for (int qt = 0; qt < 2; qt++)
#pragma unroll
      for (int r = 0; r < 4; r++) dm = fmaxf(dm, cm[qt][r] - m[qt][r]);
    if (__any(dm > 8.0f)) {  // defer-max: only rescale on real max growth
#pragma unroll
      for (int qt = 0; qt < 2; qt++)
#pragma unroll
        for (int r = 0; r < 4; r++) {
          float mn = fmaxf(m[qt][r], cm[qt][r]);
          float fr = exp2f(m[qt][r] - mn);
          m[qt][r] = mn;
          l[qt][r] *= fr;
#pragma unroll
          for (int vt = 0; vt < 4; vt++) oacc[qt][vt][r] *= fr;
        }
    }
    float ss[2][4] = {{0.f, 0.f, 0.f, 0.f}, {0.f, 0.f, 0.f, 0.f}};
#pragma unroll
    for (int qt = 0; qt < 2; qt++)
#pragma unroll
      for (int kt = 0; kt < 4; kt++)
#pragma unroll
        for (int r = 0; r < 4; r++) {
          float en = exp2f(sc[qt][kt][r] - m[qt][r]);
          sc[qt][kt][r] = en;
          ss[qt][r] += en;
        }
#pragma unroll
    for (int qt = 0; qt < 2; qt++)
#pragma unroll
      for (int r = 0; r < 4; r++) {
#pragma unroll
        for (int off = 8; off > 0; off >>= 1)
          ss[qt][r] += __shfl_xor(ss[qt][r], off, 64);
        l[qt][r] += ss[qt][r];
      }
    // ---- PV per 32-key group: packed-b32 P bounce + swizzled V from LDS
#pragma unroll
    for (int u = 0; u < 2; u++) {
      bf16x8 vf[4];
#pragma unroll
      for (int vt = 0; vt < 4; vt++)
        vf[vt] = *(const bf16x8*)(Vb_ + (vt * 16 + l15) * 128 +
                                  ((u * 64 + lg * 16) ^ swz));
#pragma unroll
      for (int qt = 0; qt < 2; qt++) {
#pragma unroll
        for (int rg = 0; rg < 4; rg++) {
          unsigned pk = (unsigned)(unsigned short)f2bf(sc[qt][2 * u][rg]) |
                        ((unsigned)(unsigned short)f2bf(sc[qt][2 * u + 1][rg]) << 16);
          *(unsigned*)(P + (lg * 4 + rg) * 80 + l15 * 4) = pk;
        }
        bf16x8 pf = *(const bf16x8*)(P + l15 * 80 + lg * 16);
#pragma unroll
        for (int vt = 0; vt < 4; vt++)
          oacc[qt][vt] = __builtin_amdgcn_mfma_f32_16x16x32_bf16(pf, vf[vt], oacc[qt][vt], 0, 0, 0);
      }
    }
  }

  int bq = c / 12, hh = c % 12;
#pragma unroll
  for (int qt = 0; qt < 2; qt++) {
    float rinv[4];
#pragma unroll
    for (int r = 0; r < 4; r++) rinv[r] = 1.0f / l[qt][r];
#pragma unroll
    for (int vt = 0; vt < 4; vt++)
#pragma unroll
      for (int r = 0; r < 4; r++) {
        size_t row = (size_t)bq * 4096 + q0 + qt * 16 + lg * 4 + r;
        AO[row * 768 + hh * 64 + vt * 16 + l15] = f2bf(oacc[qt][vt][r] * rinv[r]);
      }
  }
}

// ---------------- output GEMM (+bias), W selected per token range ----------
__global__ void __launch_bounds__(256, 2) k_gemm_out(
    const short* __restrict__ AO, const short* __restrict__ Wt,
    const float* __restrict__ bo, const float* __restrict__ bo0,
    float* __restrict__ out) {
  __shared__ short Al[128 * 32];
  __shared__ short Bl[128 * 32];
  int r0 = blockIdx.x * 128;
  int j0 = blockIdx.y * 128;
  bool o0sel = (r0 & 4095) < 256;  // first 256 tokens of each batch -> Wo0/bo0
  const short* W = Wt + (o0sel ? (size_t)1 : (size_t)0) * (768 * 768);
  const float* bias = o0sel ? bo0 : bo;
  int tid = threadIdx.x, lane = tid & 63, wid = tid >> 6;
  int wr = wid >> 1, wc = wid & 1;
  int l15 = lane & 15, lg = lane >> 4;

  f32x4 acc[4][4];
#pragma unroll
  for (int i = 0; i < 4; i++)
#pragma unroll
    for (int j = 0; j < 4; j++) acc[i][j] = fz4();

  for (int kt = 0; kt < 24; kt++) {
    int k0 = kt * 32;
#pragma unroll
    for (int i = 0; i < 2; i++) {
      int g = i * 256 + tid;
      int row = g >> 2, oct = g & 3;
      gload16(AO + (size_t)(r0 + row) * 768 + k0 + oct * 8, &Al[(i * 256 + wid * 64) * 8]);
      gload16(W + (size_t)(j0 + row) * 768 + k0 + oct * 8, &Bl[(i * 256 + wid * 64) * 8]);
    }
    __syncthreads();
    bf16x8 af[4], bfr[4];
#pragma unroll
    for (int mr = 0; mr < 4; mr++)
      af[mr] = *(const bf16x8*)&Al[(wr * 64 + mr * 16 + l15) * 32 + lg * 8];
#pragma unroll
    for (int nc = 0; nc < 4; nc++)
      bfr[nc] = *(const bf16x8*)&Bl[(wc * 64 + nc * 16 + l15) * 32 + lg * 8];
#pragma unroll
    for (int mr = 0; mr < 4; mr++)
#pragma unroll
      for (int nc = 0; nc < 4; nc++)
        acc[mr][nc] = __builtin_amdgcn_mfma_f32_16x16x32_bf16(af[mr], bfr[nc], acc[mr][nc], 0, 0, 0);
    __syncthreads();
  }

  float bs[4];
#pragma unroll
  for (int nc = 0; nc < 4; nc++) bs[nc] = bias[j0 + wc * 64 + nc * 16 + l15];
#pragma unroll
  for (int mr = 0; mr < 4; mr++)
#pragma unroll
    for (int rg = 0; rg < 4; rg++) {
      size_t r = (size_t)r0 + wr * 64 + mr * 16 + lg * 4 + rg;
      float* op = out + r * 768 + j0 + wc * 64 + l15;
      op[0]  = acc[mr][0][rg] + bs[0];
      op[16] = acc[mr][1][rg] + bs[1];
      op[32] = acc[mr][2][rg] + bs[2];
      op[48] = acc[mr][3][rg] + bs[3];
    }
}

// ---------------------------------------------------------------------------
extern "C" void kernel_launch(void* const* d_in, const int* in_sizes, int n_in,
                              void* d_out, int out_size, void* d_ws, size_t ws_size,
                              hipStream_t stream) {
  (void)in_sizes; (void)n_in; (void)out_size; (void)ws_size;
  const float* x   = (const float*)d_in[0];
  const float* Wq  = (const float*)d_in[1];
  const float* Wkv = (const float*)d_in[2];
  const float* Wo  = (const float*)d_in[3];
  const float* bo  = (const float*)d_in[4];
  const float* Wo0 = (const float*)d_in[5];
  const float* bo0 = (const float*)d_in[6];
  float* out = (float*)d_out;

  char* ws = (char*)d_ws;
  // workspace layout (bytes), total 103,022,592 (~98.3 MiB):
  //   xb/AO 0..25165824 | Qb ..50331648 | KVb ..75497472 | KVt ..100663296
  //   (WtQKV + cos/sin live INSIDE the KVt region — dead before k_transkv)
  //   WtO 100663296..103022592
  short* xb    = (short*)(ws + 0);
  short* AO    = xb;  // alias: xb dead after qkv GEMM
  short* Qb    = (short*)(ws + 25165824);
  short* KVb   = (short*)(ws + 50331648);
  short* KVt   = (short*)(ws + 75497472);
  short* WtQKV = (short*)(ws + 75497472);            // alias into KVt region
  float* cosT  = (float*)(ws + 77856768);            // alias into KVt region
  float* sinT  = (float*)(ws + 78381056);            // alias into KVt region
  short* WtO   = (short*)(ws + 100663296);

  k_rope<<<512, 256, 0, stream>>>(cosT, sinT);
  k_cvtx<<<6144, 256, 0, stream>>>(x, xb);
  k_transw<<<dim3(12, 12, 4), 256, 0, stream>>>(Wq, Wkv, Wo, Wo0, WtQKV, WtO);
  k_gemm_qkv<<<dim3(128, 12), 256, 0, stream>>>(xb, WtQKV, cosT, sinT, Qb, KVb);
  k_transkv<<<dim3(48, 64), 256, 0, stream>>>(KVb, KVt);
  k_attn<<<1536, 256, 0, stream>>>(Qb, KVb, KVt, AO);
  k_gemm_out<<<dim3(128, 6), 256, 0, stream>>>(AO, WtO, bo, bo0, out);
}

// Round 5
// 154.453 us; speedup vs baseline: 1.9449x; 1.2273x over previous
//
#include <hip/hip_runtime.h>
#include <hip/hip_bf16.h>

// ---------------------------------------------------------------------------
// LIPAR attention, MI355X. B=4 N=4096 DIM=768 H=12 DH=64 S=16 M=256 C=48.
// Pipeline: rope table | x->bf16 | W->bf16^T | qkv GEMM (+rotary,+scale,
//           Q pre-scaled by log2e for exp2-domain softmax) | KV transpose
//           (k-slot-interleaved) | flash attention (swapped-QK, fixed-base
//           softmax, ones-MFMA row sums, no P bounce) | output GEMM (+bias).
// ---------------------------------------------------------------------------

typedef float f32x4 __attribute__((ext_vector_type(4)));
typedef short bf16x8 __attribute__((ext_vector_type(8)));

#define DEV static __device__ __forceinline__

DEV short f2bf(float f) {  // RNE float->bf16 via HW cvt
  union { __hip_bfloat16 h; unsigned short u; } cv;
  cv.h = __float2bfloat16(f);
  return (short)cv.u;
}

DEV f32x4 fz4() { f32x4 z = {0.f, 0.f, 0.f, 0.f}; return z; }

DEV void gload16(const void* g, void* l) {
  // async global->LDS, 16B per lane; LDS dest = wave-uniform base + lane*16
  __builtin_amdgcn_global_load_lds((const __attribute__((address_space(1))) void*)g,
                                   (__attribute__((address_space(3))) void*)l, 16, 0, 0);
}

// ---------------- rope tables: cos/sin[pos][jm], pos<4096, jm<32 ------------
__global__ void __launch_bounds__(256) k_rope(float* __restrict__ cosT,
                                              float* __restrict__ sinT) {
  int idx = blockIdx.x * 256 + threadIdx.x;          // 131072 total
  int pos = idx >> 5, jm = idx & 31;
  float invf = exp2f(-(float)jm * (13.287712379549449f / 32.0f)); // 10000^(-jm/32)
  float th = (float)pos * invf;
  cosT[idx] = cosf(th);
  sinT[idx] = sinf(th);
}

// ---------------- x (fp32) -> xb (bf16) ------------------------------------
__global__ void __launch_bounds__(256) k_cvtx(const float* __restrict__ x,
                                              short* __restrict__ xb) {
  int i = (blockIdx.x * 256 + threadIdx.x) * 8;
  float4 a = *(const float4*)(x + i);
  float4 b = *(const float4*)(x + i + 4);
  bf16x8 v;
  v[0] = f2bf(a.x); v[1] = f2bf(a.y); v[2] = f2bf(a.z); v[3] = f2bf(a.w);
  v[4] = f2bf(b.x); v[5] = f2bf(b.y); v[6] = f2bf(b.z); v[7] = f2bf(b.w);
  *(bf16x8*)(xb + i) = v;
}

// -------- W (768x768 fp32) -> Wt[j][k] = bf16(W[k][j]) (two dest bufs) -----
__global__ void __launch_bounds__(256) k_transw(const float* __restrict__ Wq,
                                                const float* __restrict__ Wkv,
                                                const float* __restrict__ Wo,
                                                const float* __restrict__ Wo0,
                                                short* __restrict__ WtQKV,
                                                short* __restrict__ WtO) {
  __shared__ float t[64][65];
  int z = blockIdx.z;
  const float* src = (z == 0) ? Wq : (z == 1) ? Wkv : (z == 2) ? Wo : Wo0;
  short* dst = (z < 2) ? (WtQKV + (size_t)z * (768 * 768))
                       : (WtO + (size_t)(z - 2) * (768 * 768));
  int k0 = blockIdx.x * 64, j0 = blockIdx.y * 64;
  int tc = threadIdx.x & 63, tr = threadIdx.x >> 6;
#pragma unroll
  for (int i = 0; i < 16; i++) {
    int r = i * 4 + tr;
    t[tc][r] = src[(size_t)(k0 + r) * 768 + j0 + tc];   // coalesced read
  }
  __syncthreads();
#pragma unroll
  for (int i = 0; i < 16; i++) {
    int r = i * 4 + tr;
    dst[(size_t)(j0 + r) * 768 + k0 + tc] = f2bf(t[r][tc]); // coalesced write
  }
}

// ---------------- QKV GEMM 128x128 tile + fused rotary/scale ---------------
// cb 0..5 -> Q (heads 2cb+wc), cb 6..11 -> KV. Output layout [c][pos][64] bf16.
// Q additionally scaled by log2e so attention softmax can use exp2.
__global__ void __launch_bounds__(256, 2) k_gemm_qkv(
    const short* __restrict__ xb, const short* __restrict__ Wt,
    const float* __restrict__ cosT, const float* __restrict__ sinT,
    short* __restrict__ Qb, short* __restrict__ KVb) {
  __shared__ short Al[128 * 32];
  __shared__ short Bl[128 * 32];
  int r0 = blockIdx.x * 128;
  int cb = blockIdx.y;
  bool isQ = cb < 6;
  int cbl = isQ ? cb : cb - 6;
  const short* W = Wt + (isQ ? (size_t)0 : (size_t)(768 * 768));
  int j0 = cbl * 128;
  int tid = threadIdx.x, lane = tid & 63, wid = tid >> 6;
  int wr = wid >> 1, wc = wid & 1;
  int l15 = lane & 15, lg = lane >> 4;

  f32x4 acc[4][4];
#pragma unroll
  for (int i = 0; i < 4; i++)
#pragma unroll
    for (int j = 0; j < 4; j++) acc[i][j] = fz4();

  for (int kt = 0; kt < 24; kt++) {
    int k0 = kt * 32;
#pragma unroll
    for (int i = 0; i < 2; i++) {
      int g = i * 256 + tid;
      int row = g >> 2, oct = g & 3;
      gload16(xb + (size_t)(r0 + row) * 768 + k0 + oct * 8, &Al[(i * 256 + wid * 64) * 8]);
      gload16(W + (size_t)(j0 + row) * 768 + k0 + oct * 8, &Bl[(i * 256 + wid * 64) * 8]);
    }
    __syncthreads();
    bf16x8 af[4], bfr[4];
#pragma unroll
    for (int mr = 0; mr < 4; mr++)
      af[mr] = *(const bf16x8*)&Al[(wr * 64 + mr * 16 + l15) * 32 + lg * 8];
#pragma unroll
    for (int nc = 0; nc < 4; nc++)
      bfr[nc] = *(const bf16x8*)&Bl[(wc * 64 + nc * 16 + l15) * 32 + lg * 8];
#pragma unroll
    for (int mr = 0; mr < 4; mr++)
#pragma unroll
      for (int nc = 0; nc < 4; nc++)
        acc[mr][nc] = __builtin_amdgcn_mfma_f32_16x16x32_bf16(af[mr], bfr[nc], acc[mr][nc], 0, 0, 0);
    __syncthreads();
  }

  // epilogue: rotary (cols j and j^32 are acc[nc], acc[nc^2] in same lane)
  int h = 2 * cbl + wc;
  short* Ob = isQ ? Qb : KVb;
  float scl = isQ ? 0.18033688011112042f : 1.0f;  // DH^-0.5 * log2(e)
#pragma unroll
  for (int mr = 0; mr < 4; mr++) {
#pragma unroll
    for (int rg = 0; rg < 4; rg++) {
      int r = r0 + wr * 64 + mr * 16 + lg * 4 + rg;
      int b = r >> 12, pos = r & 4095;
      const float* cT = cosT + pos * 32;
      const float* sT = sinT + pos * 32;
      float c0 = cT[l15], s0 = sT[l15];
      float c1 = cT[16 + l15], s1 = sT[16 + l15];
      float v0 = acc[mr][0][rg], v1 = acc[mr][1][rg];
      float v2 = acc[mr][2][rg], v3 = acc[mr][3][rg];
      size_t base = ((size_t)((b * 12 + h) * 4096 + pos)) * 64 + l15;
      Ob[base]      = f2bf((v0 * c0 - v2 * s0) * scl);  // j<32: x*cos - x[j+32]*sin
      Ob[base + 16] = f2bf((v1 * c1 - v3 * s1) * scl);
      Ob[base + 32] = f2bf((v2 * c0 + v0 * s0) * scl);  // j>=32: x*cos + x[j-32]*sin
      Ob[base + 48] = f2bf((v3 * c1 + v1 * s1) * scl);
    }
  }
}

// ------ KV transpose, k-slot interleaved -----------------------------------
// KVt[c][d][g*32+sig] = KV[c][p][d], p = g*32 + key(sig),
// key(sig) = 4*(sig>>3) + (sig&3) + 16*((sig>>2)&1)  — matches the P-fragment
// register order of the swapped-QK attention (slot sig = lg*8 + j).
__global__ void __launch_bounds__(256) k_transkv(const short* __restrict__ KVb,
                                                 short* __restrict__ KVt) {
  __shared__ short T[64][72];
  int c = blockIdx.x;
  int pt = blockIdx.y;           // 64-pos tile
  int t = threadIdx.x;
  int ch = t & 7, rr = t >> 3;   // chunk-of-8, row (0..31)
#pragma unroll
  for (int i = 0; i < 2; i++) {
    int p = rr + i * 32;
    bf16x8 v = *(const bf16x8*)&KVb[((size_t)c * 4096 + pt * 64 + p) * 64 + ch * 8];
    *(bf16x8*)&T[p][ch * 8] = v;
  }
  __syncthreads();
#pragma unroll
  for (int i = 0; i < 2; i++) {
    int d = rr + i * 32;
    bf16x8 v;
#pragma unroll
    for (int j = 0; j < 8; j++) {
      int cc = ch * 8 + j;
      int g = cc >> 5, sig = cc & 31;
      int p = g * 32 + 4 * (sig >> 3) + (sig & 3) + 16 * ((sig >> 2) & 1);
      v[j] = T[p][d];
    }
    *(bf16x8*)&KVt[((size_t)c * 64 + d) * 4096 + pt * 64 + ch * 8] = v;
  }
}

// ---------------- flash attention (swapped-QK, fixed-base softmax) ---------
// One dispatch, 1536 blocks, XCD-bijective c-major swizzle. Block = 128 q
// (4 waves x 32q). 64-key chunks staged dbuf via global_load_lds (XOR-swizzled
// source). QK^T computed as mfma(K,Q) -> P lands with query on l15, key on
// (lg,reg) = A-fragment layout for PV (no LDS bounce). Softmax: exp2 with
// constant base 32 folded into MFMA C-init; row-sums l via ones-MFMA.
#define STAGE(buf, kk0)                                                        \
  {                                                                            \
    _Pragma("unroll") for (int i = 0; i < 2; i++) {                            \
      gload16(KVc + (size_t)((kk0) + i * 32 + krow) * 128 + ksrccol,           \
              (char*)Kl[buf] + i * 4096 + wid * 1024);                         \
      gload16(KVtc + ((size_t)(i * 32 + krow) * 4096 + (kk0)) * 2 + ksrccol,   \
              (char*)Vl[buf] + i * 4096 + wid * 1024);                         \
    }                                                                          \
  }

__global__ void __launch_bounds__(256, 4) k_attn(const short* __restrict__ Qb,
                                                 const short* __restrict__ KVbp,
                                                 const short* __restrict__ KVtp,
                                                 short* __restrict__ AO) {
  __shared__ short Kl[2][4096];    // [64 key][64 d] rows 128B, XOR-swizzled
  __shared__ short Vl[2][4096];    // [64 d][64 key(slot-interleaved)] 128B rows
  // XCD-bijective swizzle: 1536 blocks, 192/XCD, c-major so one c's KV stays
  // in one XCD's L2 (adjacent segments share half their keys).
  int bid = blockIdx.x;
  int orig = (bid & 7) * 192 + (bid >> 3);
  int c = orig >> 5;
  int e = orig & 31;               // 0,1 -> s=0 halves; 2..31 -> s=1..15 halves
  int s = (e < 2) ? 0 : ((e - 2) >> 1) + 1;
  int qh = (e < 2) ? e : (e - 2) & 1;
  int NC = (s == 0) ? 4 : 8;
  int Kbase = (s == 0) ? 0 : (s - 1) * 256;

  int tid = threadIdx.x, lane = tid & 63, wid = tid >> 6;
  int l15 = lane & 15, lg = lane >> 4;
  const char* KVc = (const char*)(KVbp + (size_t)c * 4096 * 64);
  const char* KVtc = (const char*)(KVtp + (size_t)c * 64 * 4096);

  // staging constants: row within 32-row issue, 16B chunk, swizzled src col
  int krow = tid >> 3;                 // 0..31
  int ksrccol = ((tid & 7) * 16) ^ ((krow & 7) << 4);
  int swz = (l15 & 7) << 4;            // read-side XOR

  int q0 = s * 256 + qh * 128 + wid * 32;
  bf16x8 qf[2][2];
#pragma unroll
  for (int qt = 0; qt < 2; qt++) {
    const short* Qr = Qb + ((size_t)c * 4096 + q0 + qt * 16 + l15) * 64 + lg * 8;
    qf[qt][0] = *(const bf16x8*)Qr;
    qf[qt][1] = *(const bf16x8*)(Qr + 32);
  }

  const f32x4 mi = {-32.f, -32.f, -32.f, -32.f};  // fixed softmax base
  bf16x8 ones;
#pragma unroll
  for (int j = 0; j < 8; j++) ones[j] = (short)0x3F80;  // 1.0 bf16

  f32x4 oacc[2][4];      // [qt][vt]: query=lg*4+r, d=vt*16+l15
  f32x4 lacc[2];         // [qt]: row sums (all cols identical)
#pragma unroll
  for (int qt = 0; qt < 2; qt++) {
    lacc[qt] = fz4();
#pragma unroll
    for (int vt = 0; vt < 4; vt++) oacc[qt][vt] = fz4();
  }

  STAGE(0, Kbase)
  for (int ch = 0; ch < NC; ch++) {
    int cb = ch & 1;
    __syncthreads();                       // drains vmcnt(0): buf[cb] ready
    if (ch + 1 < NC) STAGE(cb ^ 1, Kbase + (ch + 1) * 64)
    const char* Kb_ = (const char*)Kl[cb];
    const char* Vb_ = (const char*)Vl[cb];
#pragma unroll
    for (int u = 0; u < 2; u++) {          // 32-key group
      // ---- QK^T swapped: z rows = keys (lg*4+r), cols = queries (l15)
      f32x4 z[2][2];
#pragma unroll
      for (int t2 = 0; t2 < 2; t2++) {     // key tile kt = 2u+t2
        const char* Kp = Kb_ + ((2 * u + t2) * 16 + l15) * 128;
        bf16x8 kf0 = *(const bf16x8*)(Kp + ((lg * 16) ^ swz));
        bf16x8 kf1 = *(const bf16x8*)(Kp + ((64 + lg * 16) ^ swz));
        __builtin_amdgcn_s_setprio(1);
#pragma unroll
        for (int qt = 0; qt < 2; qt++) {
          f32x4 zz = __builtin_amdgcn_mfma_f32_16x16x32_bf16(kf0, qf[qt][0], mi, 0, 0, 0);
          zz = __builtin_amdgcn_mfma_f32_16x16x32_bf16(kf1, qf[qt][1], zz, 0, 0, 0);
          z[qt][t2] = zz;
        }
        __builtin_amdgcn_s_setprio(0);
      }
      // ---- P = exp2(z) (base folded into C-init), pack to A-frags
      bf16x8 pf[2];
#pragma unroll
      for (int qt = 0; qt < 2; qt++) {
#pragma unroll
        for (int t2 = 0; t2 < 2; t2++)
#pragma unroll
          for (int r = 0; r < 4; r++)
            pf[qt][t2 * 4 + r] = f2bf(exp2f(z[qt][t2][r]));
      }
      // ---- PV + ones row-sum: V^T from LDS (slot-interleaved matches pf)
      bf16x8 vf[4];
#pragma unroll
      for (int vt = 0; vt < 4; vt++)
        vf[vt] = *(const bf16x8*)(Vb_ + (vt * 16 + l15) * 128 +
                                  ((u * 64 + lg * 16) ^ swz));
      __builtin_amdgcn_s_setprio(1);
#pragma unroll
      for (int qt = 0; qt < 2; qt++) {
#pragma unroll
        for (int vt = 0; vt < 4; vt++)
          oacc[qt][vt] = __builtin_amdgcn_mfma_f32_16x16x32_bf16(pf[qt], vf[vt], oacc[qt][vt], 0, 0, 0);
        lacc[qt] = __builtin_amdgcn_mfma_f32_16x16x32_bf16(pf[qt], ones, lacc[qt], 0, 0, 0);
      }
      __builtin_amdgcn_s_setprio(0);
    }
  }

  int bq = c / 12, hh = c % 12;
#pragma unroll
  for (int qt = 0; qt < 2; qt++) {
    float rinv[4];
#pragma unroll
    for (int r = 0; r < 4; r++) rinv[r] = 1.0f / lacc[qt][r];
#pragma unroll
    for (int vt = 0; vt < 4; vt++)
#pragma unroll
      for (int r = 0; r < 4; r++) {
        size_t row = (size_t)bq * 4096 + q0 + qt * 16 + lg * 4 + r;
        AO[row * 768 + hh * 64 + vt * 16 + l15] = f2bf(oacc[qt][vt][r] * rinv[r]);
      }
  }
}

// ---------------- output GEMM (+bias), W selected per token range ----------
__global__ void __launch_bounds__(256, 2) k_gemm_out(
    const short* __restrict__ AO, const short* __restrict__ Wt,
    const float* __restrict__ bo, const float* __restrict__ bo0,
    float* __restrict__ out) {
  __shared__ short Al[128 * 32];
  __shared__ short Bl[128 * 32];
  int r0 = blockIdx.x * 128;
  int j0 = blockIdx.y * 128;
  bool o0sel = (r0 & 4095) < 256;  // first 256 tokens of each batch -> Wo0/bo0
  const short* W = Wt + (o0sel ? (size_t)1 : (size_t)0) * (768 * 768);
  const float* bias = o0sel ? bo0 : bo;
  int tid = threadIdx.x, lane = tid & 63, wid = tid >> 6;
  int wr = wid >> 1, wc = wid & 1;
  int l15 = lane & 15, lg = lane >> 4;

  f32x4 acc[4][4];
#pragma unroll
  for (int i = 0; i < 4; i++)
#pragma unroll
    for (int j = 0; j < 4; j++) acc[i][j] = fz4();

  for (int kt = 0; kt < 24; kt++) {
    int k0 = kt * 32;
#pragma unroll
    for (int i = 0; i < 2; i++) {
      int g = i * 256 + tid;
      int row = g >> 2, oct = g & 3;
      gload16(AO + (size_t)(r0 + row) * 768 + k0 + oct * 8, &Al[(i * 256 + wid * 64) * 8]);
      gload16(W + (size_t)(j0 + row) * 768 + k0 + oct * 8, &Bl[(i * 256 + wid * 64) * 8]);
    }
    __syncthreads();
    bf16x8 af[4], bfr[4];
#pragma unroll
    for (int mr = 0; mr < 4; mr++)
      af[mr] = *(const bf16x8*)&Al[(wr * 64 + mr * 16 + l15) * 32 + lg * 8];
#pragma unroll
    for (int nc = 0; nc < 4; nc++)
      bfr[nc] = *(const bf16x8*)&Bl[(wc * 64 + nc * 16 + l15) * 32 + lg * 8];
#pragma unroll
    for (int mr = 0; mr < 4; mr++)
#pragma unroll
      for (int nc = 0; nc < 4; nc++)
        acc[mr][nc] = __builtin_amdgcn_mfma_f32_16x16x32_bf16(af[mr], bfr[nc], acc[mr][nc], 0, 0, 0);
    __syncthreads();
  }

  float bs[4];
#pragma unroll
  for (int nc = 0; nc < 4; nc++) bs[nc] = bias[j0 + wc * 64 + nc * 16 + l15];
#pragma unroll
  for (int mr = 0; mr < 4; mr++)
#pragma unroll
    for (int rg = 0; rg < 4; rg++) {
      size_t r = (size_t)r0 + wr * 64 + mr * 16 + lg * 4 + rg;
      float* op = out + r * 768 + j0 + wc * 64 + l15;
      op[0]  = acc[mr][0][rg] + bs[0];
      op[16] = acc[mr][1][rg] + bs[1];
      op[32] = acc[mr][2][rg] + bs[2];
      op[48] = acc[mr][3][rg] + bs[3];
    }
}

// ---------------------------------------------------------------------------
extern "C" void kernel_launch(void* const* d_in, const int* in_sizes, int n_in,
                              void* d_out, int out_size, void* d_ws, size_t ws_size,
                              hipStream_t stream) {
  (void)in_sizes; (void)n_in; (void)out_size; (void)ws_size;
  const float* x   = (const float*)d_in[0];
  const float* Wq  = (const float*)d_in[1];
  const float* Wkv = (const float*)d_in[2];
  const float* Wo  = (const float*)d_in[3];
  const float* bo  = (const float*)d_in[4];
  const float* Wo0 = (const float*)d_in[5];
  const float* bo0 = (const float*)d_in[6];
  float* out = (float*)d_out;

  char* ws = (char*)d_ws;
  // workspace layout (bytes), total 103,022,592 (~98.3 MiB):
  //   xb/AO 0..25165824 | Qb ..50331648 | KVb ..75497472 | KVt ..100663296
  //   (WtQKV + cos/sin live INSIDE the KVt region — dead before k_transkv)
  //   WtO 100663296..103022592
  short* xb    = (short*)(ws + 0);
  short* AO    = xb;  // alias: xb dead after qkv GEMM
  short* Qb    = (short*)(ws + 25165824);
  short* KVb   = (short*)(ws + 50331648);
  short* KVt   = (short*)(ws + 75497472);
  short* WtQKV = (short*)(ws + 75497472);            // alias into KVt region
  float* cosT  = (float*)(ws + 77856768);            // alias into KVt region
  float* sinT  = (float*)(ws + 78381056);            // alias into KVt region
  short* WtO   = (short*)(ws + 100663296);

  k_rope<<<512, 256, 0, stream>>>(cosT, sinT);
  k_cvtx<<<6144, 256, 0, stream>>>(x, xb);
  k_transw<<<dim3(12, 12, 4), 256, 0, stream>>>(Wq, Wkv, Wo, Wo0, WtQKV, WtO);
  k_gemm_qkv<<<dim3(128, 12), 256, 0, stream>>>(xb, WtQKV, cosT, sinT, Qb, KVb);
  k_transkv<<<dim3(48, 64), 256, 0, stream>>>(KVb, KVt);
  k_attn<<<1536, 256, 0, stream>>>(Qb, KVb, KVt, AO);
  k_gemm_out<<<dim3(128, 6), 256, 0, stream>>>(AO, WtO, bo, bo0, out);
}